// Round 13
// baseline (112.598 us; speedup 1.0000x reference)
//
#include <hip/hip_runtime.h>
#include <hip/hip_bf16.h>
#include <math.h>

#define BATCH 1024
#define BM 64
#define BN 64
#define BK 64
#define LDK 72   // bf16 units; 144B row stride -> 16B-aligned frags, 2-way read conflicts (free)
#define NRB 16   // row-blocks = BATCH/BM
#define LDB4 472 // l4fc B-slab row stride (944B -> 2-way conflicts, free)

typedef __attribute__((ext_vector_type(8))) short bf16x8;
typedef __attribute__((ext_vector_type(8))) ushort ushort8;
typedef __attribute__((ext_vector_type(4))) float f32x4;

static __device__ __forceinline__ ushort f2bf(float f) {
    union { float f; unsigned u; } v; v.f = f;
    unsigned r = (v.u + 0x7fffu + ((v.u >> 16) & 1u)) >> 16;  // RNE
    return (ushort)r;
}
static __device__ __forceinline__ float bf2f(ushort u) {
    union { unsigned u; float f; } v; v.u = ((unsigned)u) << 16;
    return v.f;
}

struct GemmSh {
    ushort As[2][BM][LDK];
    ushort Bs[2][BN][LDK];
    float bred[4 * BN];
    float xsq_s[BM], wsq_s[BN];
    float cs[2][BN], cq[2][BN];
};
struct Sh {
    union { float ptile[64][65]; GemmSh g; } u;
    float scaleK[784], shiftK[784];
};

// ---------- stats finalize: st layout [K][NRB] float2 ----------
static __device__ __forceinline__ void finalize_stats(
    const float2* __restrict__ stats_in, const float* __restrict__ gamma,
    const float* __restrict__ beta, int K, Sh& sh, int tid)
{
    for (int k = tid; k < K; k += 256) {
        const f32x4* p4 = (const f32x4*)(stats_in + (size_t)k * NRB);
        double s = 0.0, q = 0.0;
        #pragma unroll
        for (int i = 0; i < NRB / 2; ++i) {
            f32x4 v = p4[i];
            s += (double)v[0]; q += (double)v[1];
            s += (double)v[2]; q += (double)v[3];
        }
        double mean = s * (1.0 / BATCH);
        double var = q * (1.0 / BATCH) - mean * mean;
        float inv = (float)(1.0 / sqrt(var + 1e-5));
        float sc = gamma[k] * inv;
        sh.scaleK[k] = sc;
        sh.shiftK[k] = beta[k] - (float)mean * sc;
    }
    __syncthreads();
}

// ============ fused GEMM body (BM=64, 2x2 waves of 32x32) — used by L1/L2 ============
template <int NORM, int BSRC, int ASRC, int STATS>
static __device__ void gemm_body(
    const float* __restrict__ A32, const ushort* __restrict__ A16,
    const float* __restrict__ Bw32, const ushort* __restrict__ Wt,
    const float2* __restrict__ stats_in, const float* __restrict__ gamma, const float* __restrict__ beta,
    float* __restrict__ Z, float2* __restrict__ stats_out,
    int K, int N, int cx, int rb, Sh& sh, int tid)
{
    GemmSh& G = sh.u.g;
    const int lane = tid & 63;
    const int wv = tid >> 6;
    const int wr = wv >> 1, wc = wv & 1;
    const int row0 = rb * BM, col0 = cx * BN;
    const int ar = tid >> 3;
    const int ak0 = (tid & 7) * 8;
    const int bn = tid & 63;
    const int bk0 = (tid >> 6) * 16;
    const int fr = lane & 15;
    const int fg = lane >> 4;

    if (NORM) finalize_stats(stats_in, gamma, beta, K, sh, tid);

    f32x4 acc[2][2] = {};
    float asq[2] = {0.f, 0.f};
    float bsq = 0.f;
    float areg[2][8];
    ushort8 ah[2];
    float breg[16];
    ushort8 bh[2];
    const int ntiles = (K + BK - 1) / BK;

    auto load_tile = [&](int t) {
        const int kbase = t * BK;
        const int gc = col0 + bn;
        if (kbase + BK <= K) {
            #pragma unroll
            for (int l = 0; l < 2; ++l) {
                if (ASRC == 0) {
                    const float* p = A32 + (size_t)(row0 + ar + 32 * l) * K + kbase + ak0;
                    f32x4 v0 = *(const f32x4*)p;
                    f32x4 v1 = *(const f32x4*)(p + 4);
                    #pragma unroll
                    for (int j = 0; j < 4; ++j) { areg[l][j] = v0[j]; areg[l][4 + j] = v1[j]; }
                    if (NORM) {
                        #pragma unroll
                        for (int j = 0; j < 8; ++j)
                            areg[l][j] = fmaxf(areg[l][j] * sh.scaleK[kbase + ak0 + j] + sh.shiftK[kbase + ak0 + j], 0.f);
                    }
                } else {
                    ah[l] = *(const ushort8*)(A16 + (size_t)(row0 + ar + 32 * l) * K + kbase + ak0);
                }
            }
            if (BSRC == 0) {
                #pragma unroll
                for (int i = 0; i < 16; ++i)
                    breg[i] = (gc < N) ? Bw32[(size_t)(kbase + bk0 + i) * N + gc] : 0.f;
            } else {
                if (gc < N) {
                    const ushort* q = Wt + (size_t)gc * K + kbase + bk0;
                    bh[0] = *(const ushort8*)q;
                    bh[1] = *(const ushort8*)(q + 8);
                } else {
                    bh[0] = (ushort8)0; bh[1] = (ushort8)0;
                }
            }
        } else {
            #pragma unroll
            for (int l = 0; l < 2; ++l)
                #pragma unroll
                for (int j = 0; j < 8; ++j) {
                    int gk = kbase + ak0 + j;
                    if (ASRC == 0) {
                        float x = 0.f;
                        if (gk < K) {
                            x = A32[(size_t)(row0 + ar + 32 * l) * K + gk];
                            if (NORM) x = fmaxf(x * sh.scaleK[gk] + sh.shiftK[gk], 0.f);
                        }
                        areg[l][j] = x;
                    } else {
                        ah[l][j] = (gk < K) ? A16[(size_t)(row0 + ar + 32 * l) * K + gk] : (ushort)0;
                    }
                }
            if (BSRC == 0) {
                #pragma unroll
                for (int i = 0; i < 16; ++i) {
                    int gk = kbase + bk0 + i;
                    breg[i] = (gk < K && gc < N) ? Bw32[(size_t)gk * N + gc] : 0.f;
                }
            } else {
                #pragma unroll
                for (int i = 0; i < 16; ++i) {
                    int gk = kbase + bk0 + i;
                    bh[i >> 3][i & 7] = (gk < K && gc < N) ? Wt[(size_t)gc * K + gk] : (ushort)0;
                }
            }
        }
    };

    auto store_tile = [&](int buf) {
        #pragma unroll
        for (int l = 0; l < 2; ++l) {
            if (ASRC == 0) {
                ushort8 h;
                #pragma unroll
                for (int j = 0; j < 8; ++j) {
                    h[j] = f2bf(areg[l][j]);
                    asq[l] += areg[l][j] * areg[l][j];
                }
                *(ushort8*)&G.As[buf][ar + 32 * l][ak0] = h;
            } else {
                #pragma unroll
                for (int j = 0; j < 8; ++j) {
                    float x = bf2f(ah[l][j]);
                    asq[l] += x * x;
                }
                *(ushort8*)&G.As[buf][ar + 32 * l][ak0] = ah[l];
            }
        }
        if (BSRC == 0) {
            ushort8 e0, e1;
            #pragma unroll
            for (int i = 0; i < 8; ++i) {
                e0[i] = f2bf(breg[i]);      bsq += breg[i] * breg[i];
                e1[i] = f2bf(breg[8 + i]);  bsq += breg[8 + i] * breg[8 + i];
            }
            *(ushort8*)&G.Bs[buf][bn][bk0] = e0;
            *(ushort8*)&G.Bs[buf][bn][bk0 + 8] = e1;
        } else {
            #pragma unroll
            for (int i = 0; i < 8; ++i) {
                float f0 = bf2f(bh[0][i]); bsq += f0 * f0;
                float f1 = bf2f(bh[1][i]); bsq += f1 * f1;
            }
            *(ushort8*)&G.Bs[buf][bn][bk0] = bh[0];
            *(ushort8*)&G.Bs[buf][bn][bk0 + 8] = bh[1];
        }
    };

    auto compute = [&](int buf) {
        bf16x8 af[2][2], bfr[2][2];
        #pragma unroll
        for (int m = 0; m < 2; ++m)
            #pragma unroll
            for (int kk = 0; kk < 2; ++kk)
                af[m][kk] = *(const bf16x8*)&G.As[buf][wr * 32 + m * 16 + fr][kk * 32 + fg * 8];
        #pragma unroll
        for (int n = 0; n < 2; ++n)
            #pragma unroll
            for (int kk = 0; kk < 2; ++kk)
                bfr[n][kk] = *(const bf16x8*)&G.Bs[buf][wc * 32 + n * 16 + fr][kk * 32 + fg * 8];
        #pragma unroll
        for (int m = 0; m < 2; ++m)
            #pragma unroll
            for (int n = 0; n < 2; ++n)
                #pragma unroll
                for (int kk = 0; kk < 2; ++kk)
                    acc[m][n] = __builtin_amdgcn_mfma_f32_16x16x32_bf16(af[m][kk], bfr[n][kk], acc[m][n], 0, 0, 0);
    };

    load_tile(0);
    store_tile(0);
    __syncthreads();
    for (int t = 0; t < ntiles; ++t) {
        if (t + 1 < ntiles) load_tile(t + 1);
        compute(t & 1);
        if (t + 1 < ntiles) store_tile((t + 1) & 1);
        __syncthreads();
    }

    #pragma unroll
    for (int l = 0; l < 2; ++l) {
        float s = asq[l];
        s += __shfl_xor(s, 1, 64);
        s += __shfl_xor(s, 2, 64);
        s += __shfl_xor(s, 4, 64);
        if ((tid & 7) == 0) G.xsq_s[ar + 32 * l] = s;
    }
    G.bred[(tid >> 6) * BN + bn] = bsq;
    __syncthreads();
    if (tid < BN) G.wsq_s[tid] = G.bred[0*BN+tid] + G.bred[1*BN+tid] + G.bred[2*BN+tid] + G.bred[3*BN+tid];
    __syncthreads();

    // epilogue: C/D layout col = fr, row = fg*4 + j (verified rounds 3-12)
    #pragma unroll
    for (int n = 0; n < 2; ++n) {
        const int c64 = wc * 32 + n * 16 + fr;
        const int c = col0 + c64;
        const float wsq = G.wsq_s[c64];
        float ps = 0.f, pq = 0.f;
        #pragma unroll
        for (int m = 0; m < 2; ++m) {
            #pragma unroll
            for (int j = 0; j < 4; ++j) {
                const int rl = wr * 32 + m * 16 + fg * 4 + j;
                float zv = acc[m][n][j] - 0.5f * (G.xsq_s[rl] + wsq);
                if (STATS) { ps += zv; pq += zv * zv; }
                if (c < N) Z[(size_t)(row0 + rl) * N + c] = zv;
            }
        }
        if (STATS) {
            ps += __shfl_xor(ps, 16, 64); ps += __shfl_xor(ps, 32, 64);
            pq += __shfl_xor(pq, 16, 64); pq += __shfl_xor(pq, 32, 64);
            if (fg == 0) { G.cs[wr][c64] = ps; G.cq[wr][c64] = pq; }
        }
    }
    if (STATS) {
        __syncthreads();
        if (tid < BN) {
            int c = col0 + tid;
            if (c < N)
                stats_out[(size_t)c * NRB + rb] = make_float2(G.cs[0][tid] + G.cs[1][tid],
                                                              G.cq[0][tid] + G.cq[1][tid]);
        }
    }
}

// ============ K1: L1-GEMM (112 blocks) + W2/W4 prep (32 blocks) ============
__global__ __launch_bounds__(256) void l1_kernel(
    const float* __restrict__ X, const float* __restrict__ W1,
    const float* __restrict__ W2, const float* __restrict__ W4,
    ushort* __restrict__ Wt2, ushort* __restrict__ Wt4,
    float* __restrict__ z1, float2* __restrict__ st1)
{
    __shared__ Sh sh;
    const int tid = threadIdx.x, bid = blockIdx.x;

    if (bid < 112) {
        gemm_body<0, 0, 0, 1>(X, nullptr, W1, nullptr, nullptr, nullptr, nullptr,
                              z1, st1, 784, 392, bid / 16, bid % 16, sh, tid);
        return;
    }
    for (int t = bid - 112; t < 98; t += 32) {
        const float* W; ushort* Wt; int K, N, kt, nt;
        if (t < 7) { W = W2; Wt = Wt2; K = 392; N = 8;   kt = t;      nt = 0; }
        else       { int r = t - 7; W = W4; Wt = Wt4; K = 392; N = 784; kt = r % 7; nt = r / 7; }
        const int k0 = kt * 64, n0 = nt * 64;
        #pragma unroll
        for (int it = 0; it < 16; ++it) {
            int e = it * 256 + tid;
            int kk = e >> 6, nn = e & 63;
            int gk = k0 + kk, gn = n0 + nn;
            sh.u.ptile[kk][nn] = (gk < K && gn < N) ? W[(size_t)gk * N + gn] : 0.f;
        }
        __syncthreads();
        #pragma unroll
        for (int it = 0; it < 16; ++it) {
            int e = it * 256 + tid;
            int nn = e >> 6, kk = e & 63;
            int gk = k0 + kk, gn = n0 + nn;
            if (gk < K && gn < N) Wt[(size_t)gn * K + gk] = f2bf(sh.u.ptile[kk][nn]);
        }
        __syncthreads();
    }
}

// ============ K2: L2 = relu(bn(z1)) @ Wt2 -> z2 raw ============
__global__ __launch_bounds__(256) void l2_kernel(
    const float* __restrict__ z1, const ushort* __restrict__ Wt2,
    const float2* __restrict__ st1, const float* __restrict__ g1, const float* __restrict__ b1,
    float* __restrict__ z2)
{
    __shared__ Sh sh;
    gemm_body<1, 1, 0, 0>(z1, nullptr, nullptr, Wt2, st1, g1, b1,
                          z2, nullptr, 392, 8, 0, blockIdx.x, sh, threadIdx.x);
}

// ============ K3: L3 full-column (exact fp32 middle layers) -> h3 bf16 [verified r11/r12] ============
__global__ __launch_bounds__(256) void l3fc_kernel(
    const float* __restrict__ z2, const float* __restrict__ W3,
    const float* __restrict__ g2, const float* __restrict__ b2,
    const float* __restrict__ g3, const float* __restrict__ b3,
    ushort* __restrict__ h3)
{
    __shared__ Sh sh;
    float* S = sh.scaleK;
    const int tid = threadIdx.x;
    const int c0 = blockIdx.x * 8;

    if (tid < 64) S[tid] = W3[(tid >> 3) * 392 + c0 + (tid & 7)];
    __syncthreads();
    if (tid < 8) {
        float q = 0.f;
        #pragma unroll
        for (int k = 0; k < 8; ++k) { float w = S[k * 8 + tid]; q += w * w; }
        S[64 + tid] = q;
    }

    float z[4][8];
    #pragma unroll
    for (int i = 0; i < 4; ++i) {
        const float* p = z2 + (size_t)(tid + i * 256) * 8;
        f32x4 a = *(const f32x4*)p, b = *(const f32x4*)(p + 4);
        #pragma unroll
        for (int j = 0; j < 4; ++j) { z[i][j] = a[j]; z[i][4 + j] = b[j]; }
    }

    auto blk_red8 = [&](float v[8], int outoff, float scale) {
        #pragma unroll
        for (int m = 1; m < 64; m <<= 1)
            #pragma unroll
            for (int c = 0; c < 8; ++c) v[c] += __shfl_xor(v[c], m, 64);
        if ((tid & 63) == 0) {
            #pragma unroll
            for (int c = 0; c < 8; ++c) sh.shiftK[(tid >> 6) * 8 + c] = v[c];
        }
        __syncthreads();
        if (tid < 8) S[outoff + tid] =
            (sh.shiftK[tid] + sh.shiftK[8 + tid] + sh.shiftK[16 + tid] + sh.shiftK[24 + tid]) * scale;
        __syncthreads();
    };

    float s8[8];
    #pragma unroll
    for (int c = 0; c < 8; ++c) s8[c] = z[0][c] + z[1][c] + z[2][c] + z[3][c];
    blk_red8(s8, 72, 1.f / BATCH);
    #pragma unroll
    for (int c = 0; c < 8; ++c) {
        float q = 0.f;
        #pragma unroll
        for (int i = 0; i < 4; ++i) { float d = z[i][c] - S[72 + c]; q += d * d; }
        s8[c] = q;
    }
    blk_red8(s8, 80, 1.f / BATCH);
    if (tid < 8) {
        float inv = 1.f / sqrtf(S[80 + tid] + 1e-5f);
        float sc = g2[tid] * inv;
        S[80 + tid] = sc;
        S[88 + tid] = b2[tid] - S[72 + tid] * sc;
    }
    __syncthreads();

    float h[4][8], z3v[4][8];
    #pragma unroll
    for (int i = 0; i < 4; ++i) {
        float hs = 0.f;
        #pragma unroll
        for (int c = 0; c < 8; ++c) {
            float x = fmaxf(z[i][c] * S[80 + c] + S[88 + c], 0.f);
            h[i][c] = x; hs += x * x;
        }
        #pragma unroll
        for (int c = 0; c < 8; ++c) {
            float o = 0.f;
            #pragma unroll
            for (int k = 0; k < 8; ++k) o += h[i][k] * S[k * 8 + c];
            z3v[i][c] = o - 0.5f * (hs + S[64 + c]);
        }
    }

    #pragma unroll
    for (int c = 0; c < 8; ++c) s8[c] = z3v[0][c] + z3v[1][c] + z3v[2][c] + z3v[3][c];
    blk_red8(s8, 96, 1.f / BATCH);
    #pragma unroll
    for (int c = 0; c < 8; ++c) {
        float q = 0.f;
        #pragma unroll
        for (int i = 0; i < 4; ++i) { float d = z3v[i][c] - S[96 + c]; q += d * d; }
        s8[c] = q;
    }
    blk_red8(s8, 104, 1.f / BATCH);
    if (tid < 8) {
        float inv = 1.f / sqrtf(S[104 + tid] + 1e-5f);
        float sc = g3[c0 + tid] * inv;
        S[104 + tid] = sc;
        S[112 + tid] = b3[c0 + tid] - S[96 + tid] * sc;
    }
    __syncthreads();
    #pragma unroll
    for (int i = 0; i < 4; ++i) {
        ushort8 u;
        #pragma unroll
        for (int c = 0; c < 8; ++c)
            u[c] = f2bf(fmaxf(z3v[i][c] * S[104 + c] + S[112 + c], 0.f));
        *(ushort8*)&h3[(size_t)(tid + i * 256) * 392 + c0] = u;
    }
}

// ============ K4: L4 full-column — 49 blocks, each owns 1024 rows x 16 cols ============
// B-slice (16 cols of Wt4) resident in LDS; A = h3 streamed per 64-row tile (dbuf MFMA).
// Column stats accumulated in-registers over all 16 row-tiles -> BN+sigmoid in-place. No fences.
__global__ __launch_bounds__(256) void l4fc_kernel(
    const ushort* __restrict__ h3, const ushort* __restrict__ Wt4,
    const float* __restrict__ g4, const float* __restrict__ b4,
    float* __restrict__ out)
{
    __shared__ ushort As[2][64][LDK];
    __shared__ ushort Bsl[16][LDB4];
    __shared__ float xsq_s[64];
    __shared__ float csw[4][16], cqw[4][16];
    __shared__ float wsq_s[16];
    __shared__ float sc16[16], sh16[16];

    const int tid = threadIdx.x;
    const int lane = tid & 63;
    const int w = tid >> 6;            // wave -> 16-row band within 64-row tile
    const int fr = lane & 15;          // col within 16 (and A-frag row index)
    const int fg = lane >> 4;
    const int c0 = blockIdx.x * 16;
    const int ar = tid >> 3;           // 0..31
    const int ak0 = (tid & 7) * 8;

    // stage B: 16 cols x k=0..447 (zeros past 391); K padded to 7x64
    for (int i = tid; i < 16 * 56; i += 256) {
        int col = i / 56, k0 = (i % 56) * 8;
        ushort8 v = (ushort8)0;
        if (k0 < 392) v = *(const ushort8*)(Wt4 + (size_t)(c0 + col) * 392 + k0);
        *(ushort8*)&Bsl[col][k0] = v;
    }
    __syncthreads();
    if (tid < 16) {
        float q = 0.f;
        for (int ch = 0; ch < 49; ++ch) {
            ushort8 v = *(const ushort8*)&Bsl[tid][ch * 8];
            #pragma unroll
            for (int j = 0; j < 8; ++j) { float f = bf2f(v[j]); q += f * f; }
        }
        wsq_s[tid] = q;
    }

    float ps = 0.f, pq = 0.f;          // per-col (fr) partials over all 1024 rows

    for (int rb = 0; rb < 16; ++rb) {
        const int row0 = rb * 64;
        f32x4 acc = {};
        float asq[2] = {0.f, 0.f};

        auto load_store = [&](int kt, int buf) {
            const int kbase = kt * 64;
            #pragma unroll
            for (int l = 0; l < 2; ++l) {
                int gk = kbase + ak0;
                ushort8 v = (ushort8)0;
                if (gk < 392)   // gk multiple of 8, 392 multiple of 8 -> full chunk valid
                    v = *(const ushort8*)(h3 + (size_t)(row0 + ar + 32 * l) * 392 + gk);
                #pragma unroll
                for (int j = 0; j < 8; ++j) { float f = bf2f(v[j]); asq[l] += f * f; }
                *(ushort8*)&As[buf][ar + 32 * l][ak0] = v;
            }
        };
        auto compute = [&](int kt, int buf) {
            bf16x8 af[2], bf[2];
            #pragma unroll
            for (int kk = 0; kk < 2; ++kk) {
                af[kk] = *(const bf16x8*)&As[buf][w * 16 + fr][kk * 32 + fg * 8];
                bf[kk] = *(const bf16x8*)&Bsl[fr][kt * 64 + kk * 32 + fg * 8];
            }
            #pragma unroll
            for (int kk = 0; kk < 2; ++kk)
                acc = __builtin_amdgcn_mfma_f32_16x16x32_bf16(af[kk], bf[kk], acc, 0, 0, 0);
        };

        load_store(0, 0);
        __syncthreads();
        for (int kt = 0; kt < 7; ++kt) {
            if (kt + 1 < 7) load_store(kt + 1, (kt + 1) & 1);
            compute(kt, kt & 1);
            __syncthreads();
        }

        // xsq for this 64-row tile (exact: h3 is bf16 already)
        #pragma unroll
        for (int l = 0; l < 2; ++l) {
            float s = asq[l];
            s += __shfl_xor(s, 1, 64);
            s += __shfl_xor(s, 2, 64);
            s += __shfl_xor(s, 4, 64);
            if ((tid & 7) == 0) xsq_s[ar + 32 * l] = s;
        }
        __syncthreads();

        const float wq = wsq_s[fr];
        #pragma unroll
        for (int j = 0; j < 4; ++j) {
            const int rl = w * 16 + fg * 4 + j;
            float zv = acc[j] - 0.5f * (xsq_s[rl] + wq);
            ps += zv; pq += zv * zv;
            out[(size_t)(row0 + rl) * 784 + c0 + fr] = zv;
        }
        __syncthreads();
    }

    // fold partials: lanes sharing fr (xor 16,32), then 4 waves via LDS, double finalize
    ps += __shfl_xor(ps, 16, 64); ps += __shfl_xor(ps, 32, 64);
    pq += __shfl_xor(pq, 16, 64); pq += __shfl_xor(pq, 32, 64);
    if (fg == 0) { csw[w][fr] = ps; cqw[w][fr] = pq; }
    __syncthreads();
    if (tid < 16) {
        double s = (double)csw[0][tid] + (double)csw[1][tid] + (double)csw[2][tid] + (double)csw[3][tid];
        double q = (double)cqw[0][tid] + (double)cqw[1][tid] + (double)cqw[2][tid] + (double)cqw[3][tid];
        double mean = s * (1.0 / BATCH);
        double var = q * (1.0 / BATCH) - mean * mean;
        float inv = (float)(1.0 / sqrt(var + 1e-5));
        float sc = g4[c0 + tid] * inv;
        sc16[tid] = sc;
        sh16[tid] = b4[c0 + tid] - (float)mean * sc;
    }
    __syncthreads();

    // BN + sigmoid in place over own 1024x16 slice (L2-hot)
    const int cg4 = (tid & 3) * 4;
    for (int it = 0; it < 16; ++it) {
        const int row = it * 64 + (tid >> 2);
        float* p = out + (size_t)row * 784 + c0 + cg4;
        f32x4 v = *(f32x4*)p;
        #pragma unroll
        for (int j = 0; j < 4; ++j) {
            float y = v[j] * sc16[cg4 + j] + sh16[cg4 + j];
            v[j] = 1.f / (1.f + expf(-y));
        }
        *(f32x4*)p = v;
    }
}

extern "C" void kernel_launch(void* const* d_in, const int* in_sizes, int n_in,
                              void* d_out, int out_size, void* d_ws, size_t ws_size,
                              hipStream_t stream) {
    const float* X  = (const float*)d_in[0];
    const float* W1 = (const float*)d_in[1];
    const float* g1 = (const float*)d_in[2];
    const float* b1 = (const float*)d_in[3];
    const float* W2 = (const float*)d_in[4];
    const float* g2 = (const float*)d_in[5];
    const float* b2 = (const float*)d_in[6];
    const float* W3 = (const float*)d_in[7];
    const float* g3 = (const float*)d_in[8];
    const float* b3 = (const float*)d_in[9];
    const float* W4 = (const float*)d_in[10];
    const float* g4 = (const float*)d_in[11];
    const float* b4 = (const float*)d_in[12];

    float* ws = (float*)d_ws;
    float*  z1  = ws;                               // 1024*392 f
    float*  z2  = z1 + 1024 * 392;                  // 1024*8 f
    float2* st1 = (float2*)(z2 + 1024 * 8);         // [392][16] f2
    ushort* h3  = (ushort*)(st1 + 392 * NRB);       // [1024][392] bf16
    ushort* Wt2 = h3 + 1024 * 392;                  // [8][392] bf16
    ushort* Wt4 = Wt2 + 8 * 392;                    // [784][392] bf16
    float* outp = (float*)d_out;

    // K1: L1 GEMM + W2/W4 prep
    l1_kernel<<<144, 256, 0, stream>>>(X, W1, W2, W4, Wt2, Wt4, z1, st1);
    // K2: L2 -> z2 raw
    l2_kernel<<<16, 256, 0, stream>>>(z1, Wt2, st1, g1, b1, z2);
    // K3: L3 full-column -> h3 bf16
    l3fc_kernel<<<49, 256, 0, stream>>>(z2, W3, g2, b2, g3, b3, h3);
    // K4: L4 full-column -> BN+sigmoid in place on d_out (no stats plumbing, no fences)
    l4fc_kernel<<<49, 256, 0, stream>>>(h3, Wt4, g4, b4, outp);
}

// Round 14
// 59.777 us; speedup vs baseline: 1.8836x; 1.8836x over previous
//
#include <hip/hip_runtime.h>
#include <hip/hip_bf16.h>
#include <math.h>

#define BATCH 1024
#define BM 64
#define BN 64
#define BK 64
#define LDK 72   // bf16 units; 144B row stride -> 16B-aligned frags, 2-way read conflicts (free)
#define NRB 16   // row-blocks = BATCH/BM

typedef __attribute__((ext_vector_type(8))) short bf16x8;
typedef __attribute__((ext_vector_type(8))) ushort ushort8;
typedef __attribute__((ext_vector_type(4))) float f32x4;

static __device__ __forceinline__ ushort f2bf(float f) {
    union { float f; unsigned u; } v; v.f = f;
    unsigned r = (v.u + 0x7fffu + ((v.u >> 16) & 1u)) >> 16;  // RNE
    return (ushort)r;
}
static __device__ __forceinline__ float bf2f(ushort u) {
    union { unsigned u; float f; } v; v.u = ((unsigned)u) << 16;
    return v.f;
}

struct GemmSh {
    ushort As[2][BM][LDK];
    ushort Bs[2][BN][LDK];
    float bred[4 * BN];
    float xsq_s[BM], wsq_s[BN];
    float cs[2][BN], cq[2][BN];
};
struct Sh {
    union { float ptile[64][65]; GemmSh g; } u;
    float scaleK[784], shiftK[784];
};

// ---------- stats finalize: st layout [K][NRB] float2 ----------
static __device__ __forceinline__ void finalize_stats(
    const float2* __restrict__ stats_in, const float* __restrict__ gamma,
    const float* __restrict__ beta, int K, Sh& sh, int tid)
{
    for (int k = tid; k < K; k += 256) {
        const f32x4* p4 = (const f32x4*)(stats_in + (size_t)k * NRB);
        double s = 0.0, q = 0.0;
        #pragma unroll
        for (int i = 0; i < NRB / 2; ++i) {
            f32x4 v = p4[i];
            s += (double)v[0]; q += (double)v[1];
            s += (double)v[2]; q += (double)v[3];
        }
        double mean = s * (1.0 / BATCH);
        double var = q * (1.0 / BATCH) - mean * mean;
        float inv = (float)(1.0 / sqrt(var + 1e-5));
        float sc = gamma[k] * inv;
        sh.scaleK[k] = sc;
        sh.shiftK[k] = beta[k] - (float)mean * sc;
    }
    __syncthreads();
}

// ============ fused GEMM body (BM=64, 2x2 waves of 32x32) ============
// ASRC=0: A fp32 (+optional NORM=BN+ReLU); ASRC=1: A bf16 (NORM must be 0).
// BSRC=0: B staged from fp32 W[K][N]; BSRC=1: from bf16 Wt[N][K].
// STATS=1: write per-column (sum,sumsq) partials to stats_out[c][rb].
template <int NORM, int BSRC, int ASRC, int STATS>
static __device__ void gemm_body(
    const float* __restrict__ A32, const ushort* __restrict__ A16,
    const float* __restrict__ Bw32, const ushort* __restrict__ Wt,
    const float2* __restrict__ stats_in, const float* __restrict__ gamma, const float* __restrict__ beta,
    float* __restrict__ Z, float2* __restrict__ stats_out,
    int K, int N, int cx, int rb, Sh& sh, int tid)
{
    GemmSh& G = sh.u.g;
    const int lane = tid & 63;
    const int wv = tid >> 6;
    const int wr = wv >> 1, wc = wv & 1;
    const int row0 = rb * BM, col0 = cx * BN;
    const int ar = tid >> 3;
    const int ak0 = (tid & 7) * 8;
    const int bn = tid & 63;
    const int bk0 = (tid >> 6) * 16;
    const int fr = lane & 15;
    const int fg = lane >> 4;

    if (NORM) finalize_stats(stats_in, gamma, beta, K, sh, tid);

    f32x4 acc[2][2] = {};
    float asq[2] = {0.f, 0.f};
    float bsq = 0.f;
    float areg[2][8];
    ushort8 ah[2];
    float breg[16];
    ushort8 bh[2];
    const int ntiles = (K + BK - 1) / BK;

    auto load_tile = [&](int t) {
        const int kbase = t * BK;
        const int gc = col0 + bn;
        if (kbase + BK <= K) {
            #pragma unroll
            for (int l = 0; l < 2; ++l) {
                if (ASRC == 0) {
                    const float* p = A32 + (size_t)(row0 + ar + 32 * l) * K + kbase + ak0;
                    f32x4 v0 = *(const f32x4*)p;
                    f32x4 v1 = *(const f32x4*)(p + 4);
                    #pragma unroll
                    for (int j = 0; j < 4; ++j) { areg[l][j] = v0[j]; areg[l][4 + j] = v1[j]; }
                    if (NORM) {
                        #pragma unroll
                        for (int j = 0; j < 8; ++j)
                            areg[l][j] = fmaxf(areg[l][j] * sh.scaleK[kbase + ak0 + j] + sh.shiftK[kbase + ak0 + j], 0.f);
                    }
                } else {
                    ah[l] = *(const ushort8*)(A16 + (size_t)(row0 + ar + 32 * l) * K + kbase + ak0);
                }
            }
            if (BSRC == 0) {
                #pragma unroll
                for (int i = 0; i < 16; ++i)
                    breg[i] = (gc < N) ? Bw32[(size_t)(kbase + bk0 + i) * N + gc] : 0.f;
            } else {
                if (gc < N) {
                    const ushort* q = Wt + (size_t)gc * K + kbase + bk0;
                    bh[0] = *(const ushort8*)q;
                    bh[1] = *(const ushort8*)(q + 8);
                } else {
                    bh[0] = (ushort8)0; bh[1] = (ushort8)0;
                }
            }
        } else {
            #pragma unroll
            for (int l = 0; l < 2; ++l)
                #pragma unroll
                for (int j = 0; j < 8; ++j) {
                    int gk = kbase + ak0 + j;
                    if (ASRC == 0) {
                        float x = 0.f;
                        if (gk < K) {
                            x = A32[(size_t)(row0 + ar + 32 * l) * K + gk];
                            if (NORM) x = fmaxf(x * sh.scaleK[gk] + sh.shiftK[gk], 0.f);
                        }
                        areg[l][j] = x;
                    } else {
                        ah[l][j] = (gk < K) ? A16[(size_t)(row0 + ar + 32 * l) * K + gk] : (ushort)0;
                    }
                }
            if (BSRC == 0) {
                #pragma unroll
                for (int i = 0; i < 16; ++i) {
                    int gk = kbase + bk0 + i;
                    breg[i] = (gk < K && gc < N) ? Bw32[(size_t)gk * N + gc] : 0.f;
                }
            } else {
                #pragma unroll
                for (int i = 0; i < 16; ++i) {
                    int gk = kbase + bk0 + i;
                    bh[i >> 3][i & 7] = (gk < K && gc < N) ? Wt[(size_t)gc * K + gk] : (ushort)0;
                }
            }
        }
    };

    auto store_tile = [&](int buf) {
        #pragma unroll
        for (int l = 0; l < 2; ++l) {
            if (ASRC == 0) {
                ushort8 h;
                #pragma unroll
                for (int j = 0; j < 8; ++j) {
                    h[j] = f2bf(areg[l][j]);
                    asq[l] += areg[l][j] * areg[l][j];
                }
                *(ushort8*)&G.As[buf][ar + 32 * l][ak0] = h;
            } else {
                #pragma unroll
                for (int j = 0; j < 8; ++j) {
                    float x = bf2f(ah[l][j]);
                    asq[l] += x * x;
                }
                *(ushort8*)&G.As[buf][ar + 32 * l][ak0] = ah[l];
            }
        }
        if (BSRC == 0) {
            ushort8 e0, e1;
            #pragma unroll
            for (int i = 0; i < 8; ++i) {
                e0[i] = f2bf(breg[i]);      bsq += breg[i] * breg[i];
                e1[i] = f2bf(breg[8 + i]);  bsq += breg[8 + i] * breg[8 + i];
            }
            *(ushort8*)&G.Bs[buf][bn][bk0] = e0;
            *(ushort8*)&G.Bs[buf][bn][bk0 + 8] = e1;
        } else {
            #pragma unroll
            for (int i = 0; i < 8; ++i) {
                float f0 = bf2f(bh[0][i]); bsq += f0 * f0;
                float f1 = bf2f(bh[1][i]); bsq += f1 * f1;
            }
            *(ushort8*)&G.Bs[buf][bn][bk0] = bh[0];
            *(ushort8*)&G.Bs[buf][bn][bk0 + 8] = bh[1];
        }
    };

    auto compute = [&](int buf) {
        bf16x8 af[2][2], bfr[2][2];
        #pragma unroll
        for (int m = 0; m < 2; ++m)
            #pragma unroll
            for (int kk = 0; kk < 2; ++kk)
                af[m][kk] = *(const bf16x8*)&G.As[buf][wr * 32 + m * 16 + fr][kk * 32 + fg * 8];
        #pragma unroll
        for (int n = 0; n < 2; ++n)
            #pragma unroll
            for (int kk = 0; kk < 2; ++kk)
                bfr[n][kk] = *(const bf16x8*)&G.Bs[buf][wc * 32 + n * 16 + fr][kk * 32 + fg * 8];
        #pragma unroll
        for (int m = 0; m < 2; ++m)
            #pragma unroll
            for (int n = 0; n < 2; ++n)
                #pragma unroll
                for (int kk = 0; kk < 2; ++kk)
                    acc[m][n] = __builtin_amdgcn_mfma_f32_16x16x32_bf16(af[m][kk], bfr[n][kk], acc[m][n], 0, 0, 0);
    };

    load_tile(0);
    store_tile(0);
    __syncthreads();
    for (int t = 0; t < ntiles; ++t) {
        if (t + 1 < ntiles) load_tile(t + 1);
        compute(t & 1);
        if (t + 1 < ntiles) store_tile((t + 1) & 1);
        __syncthreads();
    }

    #pragma unroll
    for (int l = 0; l < 2; ++l) {
        float s = asq[l];
        s += __shfl_xor(s, 1, 64);
        s += __shfl_xor(s, 2, 64);
        s += __shfl_xor(s, 4, 64);
        if ((tid & 7) == 0) G.xsq_s[ar + 32 * l] = s;
    }
    G.bred[(tid >> 6) * BN + bn] = bsq;
    __syncthreads();
    if (tid < BN) G.wsq_s[tid] = G.bred[0*BN+tid] + G.bred[1*BN+tid] + G.bred[2*BN+tid] + G.bred[3*BN+tid];
    __syncthreads();

    // epilogue: C/D layout col = fr, row = fg*4 + j (verified rounds 3-13)
    #pragma unroll
    for (int n = 0; n < 2; ++n) {
        const int c64 = wc * 32 + n * 16 + fr;
        const int c = col0 + c64;
        const float wsq = G.wsq_s[c64];
        float ps = 0.f, pq = 0.f;
        #pragma unroll
        for (int m = 0; m < 2; ++m) {
            #pragma unroll
            for (int j = 0; j < 4; ++j) {
                const int rl = wr * 32 + m * 16 + fg * 4 + j;
                float zv = acc[m][n][j] - 0.5f * (G.xsq_s[rl] + wsq);
                if (STATS) { ps += zv; pq += zv * zv; }
                if (c < N) Z[(size_t)(row0 + rl) * N + c] = zv;
            }
        }
        if (STATS) {
            ps += __shfl_xor(ps, 16, 64); ps += __shfl_xor(ps, 32, 64);
            pq += __shfl_xor(pq, 16, 64); pq += __shfl_xor(pq, 32, 64);
            if (fg == 0) { G.cs[wr][c64] = ps; G.cq[wr][c64] = pq; }
        }
    }
    if (STATS) {
        __syncthreads();
        if (tid < BN) {
            int c = col0 + tid;
            if (c < N)
                stats_out[(size_t)c * NRB + rb] = make_float2(G.cs[0][tid] + G.cs[1][tid],
                                                              G.cq[0][tid] + G.cq[1][tid]);
        }
    }
}

// ============ K1: L1-GEMM (112 blocks) + W2/W4 prep (32 blocks) ============
__global__ __launch_bounds__(256) void l1_kernel(
    const float* __restrict__ X, const float* __restrict__ W1,
    const float* __restrict__ W2, const float* __restrict__ W4,
    ushort* __restrict__ Wt2, ushort* __restrict__ Wt4,
    float* __restrict__ z1, float2* __restrict__ st1)
{
    __shared__ Sh sh;
    const int tid = threadIdx.x, bid = blockIdx.x;

    if (bid < 112) {
        gemm_body<0, 0, 0, 1>(X, nullptr, W1, nullptr, nullptr, nullptr, nullptr,
                              z1, st1, 784, 392, bid / 16, bid % 16, sh, tid);
        return;
    }
    for (int t = bid - 112; t < 98; t += 32) {
        const float* W; ushort* Wt; int K, N, kt, nt;
        if (t < 7) { W = W2; Wt = Wt2; K = 392; N = 8;   kt = t;      nt = 0; }
        else       { int r = t - 7; W = W4; Wt = Wt4; K = 392; N = 784; kt = r % 7; nt = r / 7; }
        const int k0 = kt * 64, n0 = nt * 64;
        #pragma unroll
        for (int it = 0; it < 16; ++it) {
            int e = it * 256 + tid;
            int kk = e >> 6, nn = e & 63;
            int gk = k0 + kk, gn = n0 + nn;
            sh.u.ptile[kk][nn] = (gk < K && gn < N) ? W[(size_t)gk * N + gn] : 0.f;
        }
        __syncthreads();
        #pragma unroll
        for (int it = 0; it < 16; ++it) {
            int e = it * 256 + tid;
            int nn = e >> 6, kk = e & 63;
            int gk = k0 + kk, gn = n0 + nn;
            if (gk < K && gn < N) Wt[(size_t)gn * K + gk] = f2bf(sh.u.ptile[kk][nn]);
        }
        __syncthreads();
    }
}

// ============ K2: L2 = relu(bn(z1)) @ Wt2 -> z2 raw (no stats) ============
__global__ __launch_bounds__(256) void l2_kernel(
    const float* __restrict__ z1, const ushort* __restrict__ Wt2,
    const float2* __restrict__ st1, const float* __restrict__ g1, const float* __restrict__ b1,
    float* __restrict__ z2)
{
    __shared__ Sh sh;
    gemm_body<1, 1, 0, 0>(z1, nullptr, nullptr, Wt2, st1, g1, b1,
                          z2, nullptr, 392, 8, 0, blockIdx.x, sh, threadIdx.x);
}

// ============ K3: L3 full-column (exact fp32 middle layers) -> h3 bf16 [verified r11-r13] ============
__global__ __launch_bounds__(256) void l3fc_kernel(
    const float* __restrict__ z2, const float* __restrict__ W3,
    const float* __restrict__ g2, const float* __restrict__ b2,
    const float* __restrict__ g3, const float* __restrict__ b3,
    ushort* __restrict__ h3)
{
    __shared__ Sh sh;
    float* S = sh.scaleK;
    const int tid = threadIdx.x;
    const int c0 = blockIdx.x * 8;

    if (tid < 64) S[tid] = W3[(tid >> 3) * 392 + c0 + (tid & 7)];
    __syncthreads();
    if (tid < 8) {
        float q = 0.f;
        #pragma unroll
        for (int k = 0; k < 8; ++k) { float w = S[k * 8 + tid]; q += w * w; }
        S[64 + tid] = q;
    }

    float z[4][8];
    #pragma unroll
    for (int i = 0; i < 4; ++i) {
        const float* p = z2 + (size_t)(tid + i * 256) * 8;
        f32x4 a = *(const f32x4*)p, b = *(const f32x4*)(p + 4);
        #pragma unroll
        for (int j = 0; j < 4; ++j) { z[i][j] = a[j]; z[i][4 + j] = b[j]; }
    }

    auto blk_red8 = [&](float v[8], int outoff, float scale) {
        #pragma unroll
        for (int m = 1; m < 64; m <<= 1)
            #pragma unroll
            for (int c = 0; c < 8; ++c) v[c] += __shfl_xor(v[c], m, 64);
        if ((tid & 63) == 0) {
            #pragma unroll
            for (int c = 0; c < 8; ++c) sh.shiftK[(tid >> 6) * 8 + c] = v[c];
        }
        __syncthreads();
        if (tid < 8) S[outoff + tid] =
            (sh.shiftK[tid] + sh.shiftK[8 + tid] + sh.shiftK[16 + tid] + sh.shiftK[24 + tid]) * scale;
        __syncthreads();
    };

    float s8[8];
    #pragma unroll
    for (int c = 0; c < 8; ++c) s8[c] = z[0][c] + z[1][c] + z[2][c] + z[3][c];
    blk_red8(s8, 72, 1.f / BATCH);
    #pragma unroll
    for (int c = 0; c < 8; ++c) {
        float q = 0.f;
        #pragma unroll
        for (int i = 0; i < 4; ++i) { float d = z[i][c] - S[72 + c]; q += d * d; }
        s8[c] = q;
    }
    blk_red8(s8, 80, 1.f / BATCH);
    if (tid < 8) {
        float inv = 1.f / sqrtf(S[80 + tid] + 1e-5f);
        float sc = g2[tid] * inv;
        S[80 + tid] = sc;
        S[88 + tid] = b2[tid] - S[72 + tid] * sc;
    }
    __syncthreads();

    float h[4][8], z3v[4][8];
    #pragma unroll
    for (int i = 0; i < 4; ++i) {
        float hs = 0.f;
        #pragma unroll
        for (int c = 0; c < 8; ++c) {
            float x = fmaxf(z[i][c] * S[80 + c] + S[88 + c], 0.f);
            h[i][c] = x; hs += x * x;
        }
        #pragma unroll
        for (int c = 0; c < 8; ++c) {
            float o = 0.f;
            #pragma unroll
            for (int k = 0; k < 8; ++k) o += h[i][k] * S[k * 8 + c];
            z3v[i][c] = o - 0.5f * (hs + S[64 + c]);
        }
    }

    #pragma unroll
    for (int c = 0; c < 8; ++c) s8[c] = z3v[0][c] + z3v[1][c] + z3v[2][c] + z3v[3][c];
    blk_red8(s8, 96, 1.f / BATCH);
    #pragma unroll
    for (int c = 0; c < 8; ++c) {
        float q = 0.f;
        #pragma unroll
        for (int i = 0; i < 4; ++i) { float d = z3v[i][c] - S[96 + c]; q += d * d; }
        s8[c] = q;
    }
    blk_red8(s8, 104, 1.f / BATCH);
    if (tid < 8) {
        float inv = 1.f / sqrtf(S[104 + tid] + 1e-5f);
        float sc = g3[c0 + tid] * inv;
        S[104 + tid] = sc;
        S[112 + tid] = b3[c0 + tid] - S[96 + tid] * sc;
    }
    __syncthreads();
    #pragma unroll
    for (int i = 0; i < 4; ++i) {
        ushort8 u;
        #pragma unroll
        for (int c = 0; c < 8; ++c)
            u[c] = f2bf(fmaxf(z3v[i][c] * S[104 + c] + S[112 + c], 0.f));
        *(ushort8*)&h3[(size_t)(tid + i * 256) * 392 + c0] = u;
    }
}

// ============ K4: L4 = h3 bf16 @ Wt4 bf16 -> z4 + st4 (parallel 208 blocks, no fences) ============
__global__ __launch_bounds__(256) void l4_kernel(
    const ushort* __restrict__ h3, const ushort* __restrict__ Wt4,
    float* __restrict__ z4, float2* __restrict__ st4)
{
    __shared__ Sh sh;
    gemm_body<0, 1, 1, 1>(nullptr, h3, nullptr, Wt4, nullptr, nullptr, nullptr,
                          z4, st4, 392, 784, blockIdx.x / 16, blockIdx.x % 16, sh, threadIdx.x);
}

// ============ K5: final BN + sigmoid, in place; block = 16-col x 128-row patch ============
__global__ __launch_bounds__(256) void bn_sigmoid_inplace(
    float* __restrict__ Zout, const float2* __restrict__ stats,
    const float* __restrict__ gamma, const float* __restrict__ beta)
{
    const int N = 784;
    const int c0 = blockIdx.x * 16;
    const int r0 = blockIdx.y * 128;
    const int tid = threadIdx.x;
    __shared__ float sc16[16], sh16[16];

    if (tid < 16) {
        int k = c0 + tid;
        const f32x4* p4 = (const f32x4*)(stats + (size_t)k * NRB);
        double s = 0.0, q = 0.0;
        #pragma unroll
        for (int i = 0; i < NRB / 2; ++i) {
            f32x4 v = p4[i];
            s += (double)v[0]; q += (double)v[1];
            s += (double)v[2]; q += (double)v[3];
        }
        double mean = s * (1.0 / BATCH);
        double var = q * (1.0 / BATCH) - mean * mean;
        float inv = (float)(1.0 / sqrt(var + 1e-5));
        float scv = gamma[k] * inv;
        sc16[tid] = scv;
        sh16[tid] = beta[k] - (float)mean * scv;
    }
    __syncthreads();

    const int row = r0 + (tid & 127);
    const int ch = tid >> 7;
    float* p = Zout + (size_t)row * N + c0 + ch * 8;
    f32x4 v0 = *(f32x4*)p;
    f32x4 v1 = *(f32x4*)(p + 4);
    #pragma unroll
    for (int j = 0; j < 4; ++j) {
        float y0 = v0[j] * sc16[ch * 8 + j] + sh16[ch * 8 + j];
        v0[j] = 1.f / (1.f + expf(-y0));
        float y1 = v1[j] * sc16[ch * 8 + 4 + j] + sh16[ch * 8 + 4 + j];
        v1[j] = 1.f / (1.f + expf(-y1));
    }
    *(f32x4*)p = v0;
    *(f32x4*)(p + 4) = v1;
}

extern "C" void kernel_launch(void* const* d_in, const int* in_sizes, int n_in,
                              void* d_out, int out_size, void* d_ws, size_t ws_size,
                              hipStream_t stream) {
    const float* X  = (const float*)d_in[0];
    const float* W1 = (const float*)d_in[1];
    const float* g1 = (const float*)d_in[2];
    const float* b1 = (const float*)d_in[3];
    const float* W2 = (const float*)d_in[4];
    const float* g2 = (const float*)d_in[5];
    const float* b2 = (const float*)d_in[6];
    const float* W3 = (const float*)d_in[7];
    const float* g3 = (const float*)d_in[8];
    const float* b3 = (const float*)d_in[9];
    const float* W4 = (const float*)d_in[10];
    const float* g4 = (const float*)d_in[11];
    const float* b4 = (const float*)d_in[12];

    float* ws = (float*)d_ws;
    float*  z1  = ws;                               // 1024*392 f
    float*  z2  = z1 + 1024 * 392;                  // 1024*8 f
    float2* st1 = (float2*)(z2 + 1024 * 8);         // [392][16] f2
    float2* st4 = st1 + 392 * NRB;                  // [784][16] f2
    ushort* h3  = (ushort*)(st4 + 784 * NRB);       // [1024][392] bf16
    ushort* Wt2 = h3 + 1024 * 392;                  // [8][392] bf16
    ushort* Wt4 = Wt2 + 8 * 392;                    // [784][392] bf16
    float* outp = (float*)d_out;

    // K1: L1 GEMM + W2/W4 prep
    l1_kernel<<<144, 256, 0, stream>>>(X, W1, W2, W4, Wt2, Wt4, z1, st1);
    // K2: L2 -> z2 raw
    l2_kernel<<<16, 256, 0, stream>>>(z1, Wt2, st1, g1, b1, z2);
    // K3: L3 full-column -> h3 bf16 (exact fp32 middle layers)
    l3fc_kernel<<<49, 256, 0, stream>>>(z2, W3, g2, b2, g3, b3, h3);
    // K4: L4 parallel GEMM -> z4 + st4
    l4_kernel<<<208, 256, 0, stream>>>(h3, Wt4, outp, st4);
    // K5: BN + sigmoid in place
    bn_sigmoid_inplace<<<dim3(49, 8), 256, 0, stream>>>(outp, st4, g4, b4);
}